// Round 1
// baseline (992.378 us; speedup 1.0000x reference)
//
#include <hip/hip_runtime.h>
#include <cstdint>
#include <cmath>

#define N_NODESC 50000
#define N_EDGESC 800000

// ---------------- workspace layout (bytes) ----------------
// QKV    : [0,          38,400,000)   N*192 f32  (Q | K | V per node row)
// counts : [38,400,000, 38,600,000)   N int
// offsets: [38,600,000, 38,800,004)   N+1 int
// cursor : [38,800,004, 39,000,004)   N int
// perm   : [39,000,004, 42,200,004)   E int  (edges sorted by dst)
// total ~42.2 MB

__global__ __launch_bounds__(256) void k_zero(int* __restrict__ p, int n) {
  int i = blockIdx.x * 256 + threadIdx.x;
  if (i < n) p[i] = 0;
}

// ---------------- QKV = x @ Wqkv^T + b  (N x 192) ----------------
// block = 256 threads, tile = 64 nodes x 192 outputs, K split in 2 halves of 32.
// LDS transposed with pad-to-odd strides -> conflict-free scalar reads (k uniform).
__global__ __launch_bounds__(256) void k_qkv(
    const float* __restrict__ x, const float* __restrict__ w,
    const float* __restrict__ bias, float* __restrict__ qkv, int N)
{
  __shared__ float wT[32 * 193];   // [k_local][j], stride 193 breaks transpose-write conflicts
  __shared__ float xT[32 * 65];    // [k_local][n], stride 65
  const int tid = threadIdx.x;
  const int node0 = blockIdx.x * 64;
  const int tn = tid & 15;         // node-quad group
  const int tj = tid >> 4;         // j-group of 12

  float acc[4][12];
#pragma unroll
  for (int i = 0; i < 4; ++i)
#pragma unroll
    for (int p = 0; p < 12; ++p) acc[i][p] = 0.f;

  for (int kh = 0; kh < 2; ++kh) {
    // W chunk: 192 j x 32 k, global-coalesced float4, LDS scalar transposed stores
#pragma unroll
    for (int it = 0; it < 6; ++it) {
      int idx4 = tid + it * 256;            // < 1536
      int j = idx4 >> 3;
      int k4 = idx4 & 7;
      float4 a = *(const float4*)&w[j * 64 + kh * 32 + k4 * 4];
      wT[(k4 * 4 + 0) * 193 + j] = a.x;
      wT[(k4 * 4 + 1) * 193 + j] = a.y;
      wT[(k4 * 4 + 2) * 193 + j] = a.z;
      wT[(k4 * 4 + 3) * 193 + j] = a.w;
    }
    // x chunk: 64 n x 32 k
#pragma unroll
    for (int it = 0; it < 2; ++it) {
      int idx4 = tid + it * 256;            // < 512
      int n = idx4 >> 3;
      int k4 = idx4 & 7;
      int gn = node0 + n;
      float4 a = make_float4(0.f, 0.f, 0.f, 0.f);
      if (gn < N) a = *(const float4*)&x[gn * 64 + kh * 32 + k4 * 4];
      xT[(k4 * 4 + 0) * 65 + n] = a.x;
      xT[(k4 * 4 + 1) * 65 + n] = a.y;
      xT[(k4 * 4 + 2) * 65 + n] = a.z;
      xT[(k4 * 4 + 3) * 65 + n] = a.w;
    }
    __syncthreads();
#pragma unroll 8
    for (int k = 0; k < 32; ++k) {
      float xa[4], wa[12];
#pragma unroll
      for (int i = 0; i < 4; ++i) xa[i] = xT[k * 65 + tn * 4 + i];
#pragma unroll
      for (int p = 0; p < 12; ++p) wa[p] = wT[k * 193 + tj * 12 + p];
#pragma unroll
      for (int i = 0; i < 4; ++i)
#pragma unroll
        for (int p = 0; p < 12; ++p)
          acc[i][p] = fmaf(xa[i], wa[p], acc[i][p]);
    }
    __syncthreads();
  }

  float b[12];
#pragma unroll
  for (int p = 0; p < 12; ++p) b[p] = bias[tj * 12 + p];
#pragma unroll
  for (int i = 0; i < 4; ++i) {
    int gn = node0 + tn * 4 + i;
    if (gn < N) {
      float* o = &qkv[gn * 192 + tj * 12];
#pragma unroll
      for (int p = 0; p < 12; ++p) o[p] = acc[i][p] + b[p];
    }
  }
}

// ---------------- Edge pass: Eh = cf @ Ew^T + Eb, conn, histogram ----------------
// One wave per edge; lane j holds E_weight rows j and j+64 in 128 VGPRs (loaded once).
// conn_feat row broadcast via per-wave LDS slot (wave-internal, in-order DS pipe, no barrier).
__global__ __launch_bounds__(256) void k_edge(
    const float* __restrict__ cf, const int* __restrict__ ei,
    const float* __restrict__ ew, const float* __restrict__ ebias,
    const float* __restrict__ qkv, float* __restrict__ conn_out,
    int* __restrict__ counts, int E)
{
  __shared__ float cfs[4][64];
  const int lane = threadIdx.x & 63;
  const int lw = threadIdx.x >> 6;
  int gw = __builtin_amdgcn_readfirstlane(blockIdx.x * 4 + lw);  // force wave-uniform -> s_loads
  const int nw = gridDim.x * 4;

  float wE[64], wB[64];
#pragma unroll
  for (int k4 = 0; k4 < 16; ++k4) {
    float4 a = *(const float4*)&ew[lane * 64 + k4 * 4];
    float4 b = *(const float4*)&ew[(lane + 64) * 64 + k4 * 4];
    wE[k4 * 4 + 0] = a.x; wE[k4 * 4 + 1] = a.y; wE[k4 * 4 + 2] = a.z; wE[k4 * 4 + 3] = a.w;
    wB[k4 * 4 + 0] = b.x; wB[k4 * 4 + 1] = b.y; wB[k4 * 4 + 2] = b.z; wB[k4 * 4 + 3] = b.w;
  }
  const float bE = ebias[lane];
  const float bB = ebias[lane + 64];

  for (int e = gw; e < E; e += nw) {
    int dst = ei[e];                       // uniform -> scalar load
    int src = ei[E + e];
    cfs[lw][lane] = cf[e * 64 + lane];     // coalesced 256B stage
    float q  = qkv[dst * 192 + lane];
    float kk = qkv[src * 192 + 64 + lane];
    __builtin_amdgcn_wave_barrier();       // keep compiler from moving LDS reads above the write
    float aE = bE, aB = bB;
#pragma unroll
    for (int k4 = 0; k4 < 16; ++k4) {
      float4 c4 = *(const float4*)&cfs[lw][k4 * 4];  // same-address broadcast, conflict-free
      aE = fmaf(c4.x, wE[k4 * 4 + 0], aE); aB = fmaf(c4.x, wB[k4 * 4 + 0], aB);
      aE = fmaf(c4.y, wE[k4 * 4 + 1], aE); aB = fmaf(c4.y, wB[k4 * 4 + 1], aB);
      aE = fmaf(c4.z, wE[k4 * 4 + 2], aE); aB = fmaf(c4.z, wB[k4 * 4 + 2], aB);
      aE = fmaf(c4.w, wE[k4 * 4 + 3], aE); aB = fmaf(c4.w, wB[k4 * 4 + 3], aB);
    }
    __builtin_amdgcn_wave_barrier();
    float s = q + kk;
    float c1 = s * aE;
    float r = sqrtf(fabsf(c1));
    float c2 = (c1 >= 0.f) ? r : -r;       // sqrt_relu(x) - sqrt_relu(-x) = sign(x)*sqrt(|x|)
    float cn = fmaxf(c2 + aB, 0.f);
    conn_out[e * 64 + lane] = cn;
    if (lane == 0) atomicAdd(&counts[dst], 1);
  }
}

// ---------------- single-block exclusive scan (CSR offsets + cursor) ----------------
__global__ void k_scan(const int* __restrict__ counts, int* __restrict__ offsets,
                       int* __restrict__ cursor, int n)
{
  __shared__ int sh[1024];
  const int tid = threadIdx.x;
  const int per = (n + 1023) >> 10;        // 49
  int start = tid * per;
  int end = start + per; if (end > n) end = n;
  int sum = 0;
  for (int i = start; i < end && start < n; ++i) sum += counts[i];
  sh[tid] = sum;
  __syncthreads();
  for (int off = 1; off < 1024; off <<= 1) {
    int t = (tid >= off) ? sh[tid - off] : 0;
    __syncthreads();
    if (tid >= off) sh[tid] += t;
    __syncthreads();
  }
  int incl = sh[tid];
  int run = incl - sum;                    // exclusive base for this thread's chunk
  for (int i = start; i < end && start < n; ++i) {
    offsets[i] = run; cursor[i] = run; run += counts[i];
  }
  if (tid == 1023) offsets[n] = incl;      // grand total
}

__global__ __launch_bounds__(256) void k_scatter(const int* __restrict__ ei,
    int* __restrict__ cursor, int* __restrict__ perm, int E)
{
  int e = blockIdx.x * 256 + threadIdx.x;
  if (e < E) {
    int dst = ei[e];
    int pos = atomicAdd(&cursor[dst], 1);
    perm[pos] = e;
  }
}

// ---------------- Node pass: online scatter-softmax + aggregation + Bw ----------------
// One wave per node; lane = h*8+d. Score recomputed from conn via shfl_xor reduce.
__global__ __launch_bounds__(256) void k_node(
    const int* __restrict__ ei, const int* __restrict__ offsets,
    const int* __restrict__ perm, const float* __restrict__ conn,
    const float* __restrict__ qkv, const float* __restrict__ Aw,
    const float* __restrict__ Bw, float* __restrict__ No, int N, int E)
{
  const int lane = threadIdx.x & 63;
  int node = blockIdx.x * 4 + (threadIdx.x >> 6);
  node = __builtin_amdgcn_readfirstlane(node);
  if (node >= N) return;

  const float awv = Aw[(lane & 7) * 8 + (lane >> 3)];  // Aw[d, h, 0]
  float bw[8];
#pragma unroll
  for (int dd = 0; dd < 8; ++dd) bw[dd] = Bw[dd * 64 + lane];  // Bw[d, h, c]

  const int beg = offsets[node];
  const int end = offsets[node + 1];
  float m = -INFINITY, l = 0.f, aV = 0.f, aC = 0.f;

  for (int i = beg; i < end; ++i) {
    int e = perm[i];                        // uniform -> scalar load
    int src = ei[E + e];
    float c = conn[e * 64 + lane];          // coalesced 256B
    float v = qkv[src * 192 + 128 + lane];  // V row, coalesced 256B
    float t = c * awv;                      // per-head dot over d via 8-lane butterfly
    t += __shfl_xor(t, 1, 64);
    t += __shfl_xor(t, 2, 64);
    t += __shfl_xor(t, 4, 64);
    float s = fminf(fmaxf(t, -5.f), 5.f);
    float mn = fmaxf(m, s);
    float al = __expf(m - mn);              // first iter: exp(-inf)=0
    float wgt = __expf(s - mn);
    l  = l * al + wgt;
    aV = fmaf(wgt, v, aV * al);
    aC = fmaf(wgt, c, aC * al);
    m = mn;
  }

  float inv = 1.f / (l + 1e-16f);           // zero-degree nodes -> 0 output
  float rowv = aC * inv;                    // rowV[n,h,d] at lane (h,d)
  float acc = aV * inv;                     // agg[n,h,c] at lane (h,c)
  const int hbase = lane & 56;
#pragma unroll
  for (int dd = 0; dd < 8; ++dd) {
    float rr = __shfl(rowv, hbase + dd, 64);
    acc = fmaf(rr, bw[dd], acc);
  }
  No[node * 64 + lane] = acc;
}

extern "C" void kernel_launch(void* const* d_in, const int* in_sizes, int n_in,
                              void* d_out, int out_size, void* d_ws, size_t ws_size,
                              hipStream_t stream)
{
  const float* x  = (const float*)d_in[0];
  const float* cf = (const float*)d_in[1];
  const int*   ei = (const int*)d_in[2];
  const float* qw = (const float*)d_in[3];
  const float* qb = (const float*)d_in[4];
  const float* ew = (const float*)d_in[5];
  const float* eb = (const float*)d_in[6];
  const float* Aw = (const float*)d_in[7];
  const float* Bw = (const float*)d_in[8];

  float* No   = (float*)d_out;                                // (N, 64)
  float* conn = (float*)d_out + (size_t)N_NODESC * 64;        // (E, 64)

  char* ws = (char*)d_ws;                                     // needs ~42.2 MB
  float* QKV   = (float*)(ws);
  int* counts  = (int*)(ws + 38400000);
  int* offsets = (int*)(ws + 38600000);
  int* cursor  = (int*)(ws + 38800004);
  int* perm    = (int*)(ws + 39000004);

  k_zero<<<(N_NODESC + 255) / 256, 256, 0, stream>>>(counts, N_NODESC);
  k_qkv<<<(N_NODESC + 63) / 64, 256, 0, stream>>>(x, qw, qb, QKV, N_NODESC);
  k_edge<<<1024, 256, 0, stream>>>(cf, ei, ew, eb, QKV, conn, counts, N_EDGESC);
  k_scan<<<1, 1024, 0, stream>>>(counts, offsets, cursor, N_NODESC);
  k_scatter<<<(N_EDGESC + 255) / 256, 256, 0, stream>>>(ei, cursor, perm, N_EDGESC);
  k_node<<<N_NODESC / 4, 256, 0, stream>>>(ei, offsets, perm, conn, QKV, Aw, Bw, No, N_NODESC, N_EDGESC);
}

// Round 2
// 825.901 us; speedup vs baseline: 1.2016x; 1.2016x over previous
//
#include <hip/hip_runtime.h>
#include <cstdint>
#include <cmath>

#define N_NODESC 50000
#define N_EDGESC 800000

// ---------------- workspace layout (bytes) ----------------
// QKV    : [0,          38,400,000)   N*192 f32  (Q | K | V per node row)
// counts : [38,400,000, 38,600,000)   N int
// offsets: [38,600,000, 38,800,004)   N+1 int
// cursor : [38,800,004, 39,000,004)   N int
// perm   : [39,000,004, 42,200,004)   E int  (edges sorted by dst)
// total ~42.2 MB

__global__ __launch_bounds__(256) void k_zero(int* __restrict__ p, int n) {
  int i = blockIdx.x * 256 + threadIdx.x;
  if (i < n) p[i] = 0;
}

// ---------------- QKV = x @ Wqkv^T + b  (N x 192) ----------------
__global__ __launch_bounds__(256) void k_qkv(
    const float* __restrict__ x, const float* __restrict__ w,
    const float* __restrict__ bias, float* __restrict__ qkv, int N)
{
  __shared__ float wT[32 * 193];
  __shared__ float xT[32 * 65];
  const int tid = threadIdx.x;
  const int node0 = blockIdx.x * 64;
  const int tn = tid & 15;
  const int tj = tid >> 4;

  float acc[4][12];
#pragma unroll
  for (int i = 0; i < 4; ++i)
#pragma unroll
    for (int p = 0; p < 12; ++p) acc[i][p] = 0.f;

  for (int kh = 0; kh < 2; ++kh) {
#pragma unroll
    for (int it = 0; it < 6; ++it) {
      int idx4 = tid + it * 256;
      int j = idx4 >> 3;
      int k4 = idx4 & 7;
      float4 a = *(const float4*)&w[j * 64 + kh * 32 + k4 * 4];
      wT[(k4 * 4 + 0) * 193 + j] = a.x;
      wT[(k4 * 4 + 1) * 193 + j] = a.y;
      wT[(k4 * 4 + 2) * 193 + j] = a.z;
      wT[(k4 * 4 + 3) * 193 + j] = a.w;
    }
#pragma unroll
    for (int it = 0; it < 2; ++it) {
      int idx4 = tid + it * 256;
      int n = idx4 >> 3;
      int k4 = idx4 & 7;
      int gn = node0 + n;
      float4 a = make_float4(0.f, 0.f, 0.f, 0.f);
      if (gn < N) a = *(const float4*)&x[gn * 64 + kh * 32 + k4 * 4];
      xT[(k4 * 4 + 0) * 65 + n] = a.x;
      xT[(k4 * 4 + 1) * 65 + n] = a.y;
      xT[(k4 * 4 + 2) * 65 + n] = a.z;
      xT[(k4 * 4 + 3) * 65 + n] = a.w;
    }
    __syncthreads();
#pragma unroll 8
    for (int k = 0; k < 32; ++k) {
      float xa[4], wa[12];
#pragma unroll
      for (int i = 0; i < 4; ++i) xa[i] = xT[k * 65 + tn * 4 + i];
#pragma unroll
      for (int p = 0; p < 12; ++p) wa[p] = wT[k * 193 + tj * 12 + p];
#pragma unroll
      for (int i = 0; i < 4; ++i)
#pragma unroll
        for (int p = 0; p < 12; ++p)
          acc[i][p] = fmaf(xa[i], wa[p], acc[i][p]);
    }
    __syncthreads();
  }

  float b[12];
#pragma unroll
  for (int p = 0; p < 12; ++p) b[p] = bias[tj * 12 + p];
#pragma unroll
  for (int i = 0; i < 4; ++i) {
    int gn = node0 + tn * 4 + i;
    if (gn < N) {
      float* o = &qkv[gn * 192 + tj * 12];
#pragma unroll
      for (int p = 0; p < 12; ++p) o[p] = acc[i][p] + b[p];
    }
  }
}

// ---------------- Edge pass: tiled GEMM (E x 64) @ (64 x 128) + fused epilogue ----
// Block: 128 edges x 128 cols, 256 threads; thread (te,tj) owns edges
// {te*4+i, 64+te*4+i} and cols {tj*4+c (Ew), 64+tj*4+c (Eb)} -> 2x4x8 = 64 acc.
// LDS: aT[k][e] and bT[k][j], both XOR-swizzled in groups of 4 so the transpose
// STORES are <=2-way bank-conflicted while fragment READS stay ds_read_b128.
__global__ __launch_bounds__(256) void k_edge(
    const float* __restrict__ cf, const int* __restrict__ ei,
    const float* __restrict__ ew, const float* __restrict__ ebias,
    const float* __restrict__ qkv, float* __restrict__ conn_out,
    int* __restrict__ counts, int E)
{
  __shared__ float aT[64 * 128];   // [k][e swizzled]  32 KB
  __shared__ float bT[64 * 128];   // [k][j swizzled]  32 KB
  const int tid = threadIdx.x;
  const int e0 = blockIdx.x * 128;
  const int te = tid >> 4;         // [0,16) edge group
  const int tj = tid & 15;         // [0,16) col group

  // ---- stage B: bT[k][swz(j)] = ew[j*64+k]   (128 rows j, 64 k)
#pragma unroll
  for (int it = 0; it < 8; ++it) {
    int idx = tid + it * 256;              // [0,2048)
    int j = idx >> 4;                      // [0,128)
    int k4 = idx & 15;
    float4 a = *(const float4*)&ew[j * 64 + k4 * 4];
    int js = (((j >> 2) ^ k4) << 2) | (j & 3);
    bT[(k4 * 4 + 0) * 128 + js] = a.x;
    bT[(k4 * 4 + 1) * 128 + js] = a.y;
    bT[(k4 * 4 + 2) * 128 + js] = a.z;
    bT[(k4 * 4 + 3) * 128 + js] = a.w;
  }
  // ---- stage A: aT[k][swz(e)] = cf[(e0+e)*64+k]
#pragma unroll
  for (int it = 0; it < 8; ++it) {
    int idx = tid + it * 256;
    int e = idx >> 4;
    int k4 = idx & 15;
    float4 a = *(const float4*)&cf[(e0 + e) * 64 + k4 * 4];
    int es = (((e >> 2) ^ k4) << 2) | (e & 3);
    aT[(k4 * 4 + 0) * 128 + es] = a.x;
    aT[(k4 * 4 + 1) * 128 + es] = a.y;
    aT[(k4 * 4 + 2) * 128 + es] = a.z;
    aT[(k4 * 4 + 3) * 128 + es] = a.w;
  }
  __syncthreads();

  float acc[2][4][8];
#pragma unroll
  for (int g = 0; g < 2; ++g)
#pragma unroll
    for (int i = 0; i < 4; ++i)
#pragma unroll
      for (int c = 0; c < 8; ++c) acc[g][i][c] = 0.f;

#pragma unroll 2
  for (int k4 = 0; k4 < 16; ++k4) {
    const int sA0 = ((te ^ k4) << 2);      // edge group g=0 (eg = te)
    const int sB0 = ((tj ^ k4) << 2);      // col  group Ew (jg = tj)
#pragma unroll
    for (int c = 0; c < 4; ++c) {
      const int k = k4 * 4 + c;
      float4 a0 = *(const float4*)&aT[k * 128 + sA0];
      float4 a1 = *(const float4*)&aT[k * 128 + sA0 + 64];   // eg = 16+te
      float4 b0 = *(const float4*)&bT[k * 128 + sB0];
      float4 b1 = *(const float4*)&bT[k * 128 + sB0 + 64];   // jg = 16+tj
      const float av0[4] = {a0.x, a0.y, a0.z, a0.w};
      const float av1[4] = {a1.x, a1.y, a1.z, a1.w};
      const float bv0[4] = {b0.x, b0.y, b0.z, b0.w};
      const float bv1[4] = {b1.x, b1.y, b1.z, b1.w};
#pragma unroll
      for (int i = 0; i < 4; ++i)
#pragma unroll
        for (int j = 0; j < 4; ++j) {
          acc[0][i][j]     = fmaf(av0[i], bv0[j], acc[0][i][j]);
          acc[0][i][4 + j] = fmaf(av0[i], bv1[j], acc[0][i][4 + j]);
          acc[1][i][j]     = fmaf(av1[i], bv0[j], acc[1][i][j]);
          acc[1][i][4 + j] = fmaf(av1[i], bv1[j], acc[1][i][4 + j]);
        }
    }
  }

  // ---- fused epilogue: conn = relu(sign_sqrt((Q[dst]+K[src])*Ew) + Eb)
  float bE[4], bB[4];
#pragma unroll
  for (int c = 0; c < 4; ++c) {
    bE[c] = ebias[tj * 4 + c];
    bB[c] = ebias[64 + tj * 4 + c];
  }
#pragma unroll
  for (int g = 0; g < 2; ++g)
#pragma unroll
    for (int i = 0; i < 4; ++i) {
      const int el = g * 64 + te * 4 + i;
      const int e = e0 + el;
      const int dst = ei[e];
      const int src = ei[E + e];
      float4 q  = *(const float4*)&qkv[dst * 192 + tj * 4];
      float4 kk = *(const float4*)&qkv[src * 192 + 64 + tj * 4];
      const float qv[4] = {q.x, q.y, q.z, q.w};
      const float kv[4] = {kk.x, kk.y, kk.z, kk.w};
      float4 out;
      float ov[4];
#pragma unroll
      for (int c = 0; c < 4; ++c) {
        float aE = acc[g][i][c] + bE[c];
        float aB = acc[g][i][4 + c] + bB[c];
        float s = (qv[c] + kv[c]) * aE;
        float r = sqrtf(fabsf(s));
        float c2 = (s >= 0.f) ? r : -r;    // sqrt_relu(x)-sqrt_relu(-x)
        ov[c] = fmaxf(c2 + aB, 0.f);
      }
      out.x = ov[0]; out.y = ov[1]; out.z = ov[2]; out.w = ov[3];
      *(float4*)&conn_out[(size_t)e * 64 + tj * 4] = out;
      if (tj == 0) atomicAdd(&counts[dst], 1);
    }
}

// ---------------- single-block exclusive scan (CSR offsets + cursor) ----------------
__global__ void k_scan(const int* __restrict__ counts, int* __restrict__ offsets,
                       int* __restrict__ cursor, int n)
{
  __shared__ int sh[1024];
  const int tid = threadIdx.x;
  const int per = (n + 1023) >> 10;
  int start = tid * per;
  int end = start + per; if (end > n) end = n;
  int sum = 0;
  for (int i = start; i < end && start < n; ++i) sum += counts[i];
  sh[tid] = sum;
  __syncthreads();
  for (int off = 1; off < 1024; off <<= 1) {
    int t = (tid >= off) ? sh[tid - off] : 0;
    __syncthreads();
    if (tid >= off) sh[tid] += t;
    __syncthreads();
  }
  int incl = sh[tid];
  int run = incl - sum;
  for (int i = start; i < end && start < n; ++i) {
    offsets[i] = run; cursor[i] = run; run += counts[i];
  }
  if (tid == 1023) offsets[n] = incl;
}

__global__ __launch_bounds__(256) void k_scatter(const int* __restrict__ ei,
    int* __restrict__ cursor, int* __restrict__ perm, int E)
{
  int e = blockIdx.x * 256 + threadIdx.x;
  if (e < E) {
    int dst = ei[e];
    int pos = atomicAdd(&cursor[dst], 1);
    perm[pos] = e;
  }
}

// ---------------- Node pass: online scatter-softmax + aggregation + Bw ----------------
// One wave per node; lane = h*8+d. Next edge's conn/V rows are prefetched before
// the dependent exp-chain to hide gather latency.
__global__ __launch_bounds__(256) void k_node(
    const int* __restrict__ ei, const int* __restrict__ offsets,
    const int* __restrict__ perm, const float* __restrict__ conn,
    const float* __restrict__ qkv, const float* __restrict__ Aw,
    const float* __restrict__ Bw, float* __restrict__ No, int N, int E)
{
  const int lane = threadIdx.x & 63;
  int node = blockIdx.x * 4 + (threadIdx.x >> 6);
  node = __builtin_amdgcn_readfirstlane(node);
  if (node >= N) return;

  const float awv = Aw[(lane & 7) * 8 + (lane >> 3)];  // Aw[d, h, 0]
  float bw[8];
#pragma unroll
  for (int dd = 0; dd < 8; ++dd) bw[dd] = Bw[dd * 64 + lane];  // Bw[d, h, c]

  const int beg = offsets[node];
  const int end = offsets[node + 1];
  float m = -INFINITY, l = 0.f, aV = 0.f, aC = 0.f;

  float c_nxt = 0.f, v_nxt = 0.f;
  if (beg < end) {
    int e = perm[beg];
    int src = ei[E + e];
    c_nxt = conn[(size_t)e * 64 + lane];
    v_nxt = qkv[src * 192 + 128 + lane];
  }
  for (int i = beg; i < end; ++i) {
    float c = c_nxt;
    float v = v_nxt;
    if (i + 1 < end) {                     // prefetch next edge before exp chain
      int e2 = perm[i + 1];
      int s2 = ei[E + e2];
      c_nxt = conn[(size_t)e2 * 64 + lane];
      v_nxt = qkv[s2 * 192 + 128 + lane];
    }
    float t = c * awv;
    t += __shfl_xor(t, 1, 64);
    t += __shfl_xor(t, 2, 64);
    t += __shfl_xor(t, 4, 64);
    float s = fminf(fmaxf(t, -5.f), 5.f);
    float mn = fmaxf(m, s);
    float al = __expf(m - mn);
    float wgt = __expf(s - mn);
    l  = l * al + wgt;
    aV = fmaf(wgt, v, aV * al);
    aC = fmaf(wgt, c, aC * al);
    m = mn;
  }

  float inv = 1.f / (l + 1e-16f);
  float rowv = aC * inv;
  float acc = aV * inv;
  const int hbase = lane & 56;
#pragma unroll
  for (int dd = 0; dd < 8; ++dd) {
    float rr = __shfl(rowv, hbase + dd, 64);
    acc = fmaf(rr, bw[dd], acc);
  }
  No[node * 64 + lane] = acc;
}

extern "C" void kernel_launch(void* const* d_in, const int* in_sizes, int n_in,
                              void* d_out, int out_size, void* d_ws, size_t ws_size,
                              hipStream_t stream)
{
  const float* x  = (const float*)d_in[0];
  const float* cf = (const float*)d_in[1];
  const int*   ei = (const int*)d_in[2];
  const float* qw = (const float*)d_in[3];
  const float* qb = (const float*)d_in[4];
  const float* ew = (const float*)d_in[5];
  const float* eb = (const float*)d_in[6];
  const float* Aw = (const float*)d_in[7];
  const float* Bw = (const float*)d_in[8];

  float* No   = (float*)d_out;
  float* conn = (float*)d_out + (size_t)N_NODESC * 64;

  char* ws = (char*)d_ws;
  float* QKV   = (float*)(ws);
  int* counts  = (int*)(ws + 38400000);
  int* offsets = (int*)(ws + 38600000);
  int* cursor  = (int*)(ws + 38800004);
  int* perm    = (int*)(ws + 39000004);

  k_zero<<<(N_NODESC + 255) / 256, 256, 0, stream>>>(counts, N_NODESC);
  k_qkv<<<(N_NODESC + 63) / 64, 256, 0, stream>>>(x, qw, qb, QKV, N_NODESC);
  k_edge<<<N_EDGESC / 128, 256, 0, stream>>>(cf, ei, ew, eb, QKV, conn, counts, N_EDGESC);
  k_scan<<<1, 1024, 0, stream>>>(counts, offsets, cursor, N_NODESC);
  k_scatter<<<(N_EDGESC + 255) / 256, 256, 0, stream>>>(ei, cursor, perm, N_EDGESC);
  k_node<<<N_NODESC / 4, 256, 0, stream>>>(ei, offsets, perm, conn, QKV, Aw, Bw, No, N_NODESC, N_EDGESC);
}